// Round 9
// baseline (429.353 us; speedup 1.0000x reference)
//
#include <hip/hip_runtime.h>

#define N_NODES 50000
#define N_EDGES 800000
#define N_B 2
#define N_C 64
#define BN_ROWS (N_B * N_NODES)
#define NBKT 196          // ceil(50000/256) row buckets
#define PCAP 32           // LDS queue entries per bucket in k_part

typedef __attribute__((ext_vector_type(8))) short short8;   // 8 bf16 = 4 VGPR
typedef __attribute__((ext_vector_type(4))) float f32x4;    // MFMA accum

__device__ inline unsigned short f2bf(float f) {
  unsigned int u = __float_as_uint(f);
  return (unsigned short)((u + 0x7fffu + ((u >> 16) & 1u)) >> 16);  // RNE
}
__device__ inline float bf2f(unsigned short h) { return __uint_as_float(((unsigned int)h) << 16); }
__device__ inline float lof(unsigned int u) { return __uint_as_float(u << 16); }
__device__ inline float hif(unsigned int u) { return __uint_as_float(u & 0xffff0000u); }

// ---------------- degree count (non-self-loop edges per source row) ----------
__global__ __launch_bounds__(256) void k_deg(const int* __restrict__ ei, int* __restrict__ deg) {
  int e = blockIdx.x * 256 + threadIdx.x;
  if (e >= N_EDGES) return;
  int r = ei[e];
  int c = ei[N_EDGES + e];
  if (r != c) atomicAdd(&deg[r], 1);
}

// ---------------- per-bucket degree sums + dis = deg^-1/2 --------------------
__global__ __launch_bounds__(256) void k_bsum(const int* __restrict__ deg, float* __restrict__ dis,
                                              int* __restrict__ bsum) {
  __shared__ int wsum[4];
  int t = threadIdx.x;
  int n = blockIdx.x * 256 + t;
  int d = (n < N_NODES) ? deg[n] : 0;
  if (n < N_NODES) dis[n] = d > 0 ? rsqrtf((float)d) : 0.0f;
  int s = d;
#pragma unroll
  for (int off = 1; off < 64; off <<= 1) s += __shfl_xor(s, off);
  if ((t & 63) == 0) wsum[t >> 6] = s;
  __syncthreads();
  if (t == 0) bsum[blockIdx.x] = wsum[0] + wsum[1] + wsum[2] + wsum[3];
}

// ---------------- exclusive scan of bucket sums -> bucket bases --------------
__global__ __launch_bounds__(256) void k_scanb(const int* __restrict__ bsum, int* __restrict__ stageBase,
                                               int* __restrict__ stageCur) {
  __shared__ int sa[256];
  __shared__ int sb[256];
  int t = threadIdx.x;
  int v = (t < NBKT) ? bsum[t] : 0;
  sa[t] = v;
  __syncthreads();
  int* src = sa; int* dst = sb;
  for (int off = 1; off < 256; off <<= 1) {
    int x = src[t];
    if (t >= off) x += src[t - off];
    dst[t] = x;
    __syncthreads();
    int* tmp = src; src = dst; dst = tmp;
  }
  int excl = src[t] - v;
  if (t < NBKT) { stageBase[t] = excl; stageCur[t] = excl; }
}

// ---------------- partition edges into row buckets (LDS write-combining) -----
// Round-8 diagnosis: k_fill's random 8B scatters caused 52MB of line-granular
// writes (8x amplification) + per-edge device atomic chains -> 46us at 0.7%
// VALU. Here each block LDS-queues (val,row_lo,col) 8B payloads per bucket and
// flushes contiguous runs (avg ~21 entries) with ONE global atomic per run.
// Statistical overflow (pos>=PCAP, ~300 edges total) goes direct -- correct,
// just unbatched. Staging lives in the t1h buffer (unused until spmm1).
__global__ __launch_bounds__(256) void k_part(const int* __restrict__ ei, const float* __restrict__ ew,
                                              const float* __restrict__ dis, int* __restrict__ stageCur,
                                              unsigned long long* __restrict__ stage) {
  __shared__ unsigned long long sbuf[NBKT * PCAP];  // 50KB
  __shared__ int scnt[NBKT];
  int t = threadIdx.x;
  for (int i = t; i < NBKT; i += 256) scnt[i] = 0;
  __syncthreads();
  int e0 = blockIdx.x * 4096;
#pragma unroll 1
  for (int rnd = 0; rnd < 16; ++rnd) {
    int e = e0 + rnd * 256 + t;
    if (e < N_EDGES) {
      int r = ei[e];
      int c = ei[N_EDGES + e];
      if (r != c) {
        float v = -dis[r] * ew[e] * dis[c];
        int b = r >> 8;
        unsigned long long p = ((unsigned long long)__float_as_uint(v) << 32)
                             | ((unsigned long long)(r & 255) << 16) | (unsigned)c;
        int pos = atomicAdd(&scnt[b], 1);
        if (pos < PCAP) {
          sbuf[b * PCAP + pos] = p;
        } else {
          int g = atomicAdd(&stageCur[b], 1);
          stage[g] = p;
        }
      }
    }
  }
  __syncthreads();
  int wave = t >> 6, lane = t & 63;
  for (int b = wave; b < NBKT; b += 4) {
    int nl = scnt[b];
    if (nl > PCAP) nl = PCAP;
    if (nl == 0) continue;
    int gbase;
    if (lane == 0) gbase = atomicAdd(&stageCur[b], nl);
    gbase = __shfl(gbase, 0);
    if (lane < nl) stage[gbase + lane] = sbuf[b * PCAP + lane];
  }
}

// ---------------- build ordered CSR within each bucket (LDS cursors) ---------
// One block per bucket: scan 256 degs -> rowptr; place edges via LDS atomics
// into the bucket's ~32KB CSR window (L2-resident lines, ~8 writes each).
__global__ __launch_bounds__(256) void k_build(const int* __restrict__ deg, const int* __restrict__ stageBase,
                                               const unsigned long long* __restrict__ stage,
                                               int* __restrict__ rowptr, int2* __restrict__ ccv) {
  __shared__ int sa[256];
  __shared__ int sb[256];
  __shared__ int cur[256];
  __shared__ int shr[2];
  int t = threadIdx.x;
  int n = blockIdx.x * 256 + t;
  int d = (n < N_NODES) ? deg[n] : 0;
  sa[t] = d;
  __syncthreads();
  int* src = sa; int* dst = sb;
  for (int off = 1; off < 256; off <<= 1) {
    int x = src[t];
    if (t >= off) x += src[t - off];
    dst[t] = x;
    __syncthreads();
    int* tmp = src; src = dst; dst = tmp;
  }
  int excl = src[t] - d;
  cur[t] = excl;
  if (t == 255) shr[0] = src[255];               // bucket edge count
  if (t == 0) shr[1] = stageBase[blockIdx.x];    // bucket base
  __syncthreads();
  int cnt = shr[0], base = shr[1];
  if (n < N_NODES) rowptr[n] = base + excl;
  for (int i = t; i < cnt; i += 256) {
    unsigned long long p = stage[base + i];
    int c = (int)(p & 0xFFFFu);
    int rl = (int)((p >> 16) & 0xFFu);
    unsigned int vb = (unsigned int)(p >> 32);
    int pos = atomicAdd(&cur[rl], 1);
    ccv[base + pos] = make_int2(c, (int)vb);
  }
}

// ---------------- x (fp32) -> bf16 copy --------------------------------------
__global__ __launch_bounds__(256) void k_cvt(const float* __restrict__ x, unsigned short* __restrict__ xb) {
  int i = blockIdx.x * 256 + threadIdx.x;  // float4-quad index
  if (i >= BN_ROWS * 16) return;
  float4 v = ((const float4*)x)[i];
  ushort4 h;
  h.x = f2bf(v.x); h.y = f2bf(v.y); h.z = f2bf(v.z); h.w = f2bf(v.w);
  ((ushort4*)xb)[i] = h;
}

// ---------------- SPMM: dst[b,n,:] = sum_e lap_e * src[b,col_e,:] ------------
// One wave per NODE, BOTH batches. lane = (edge-slot g = l>>3) x (channel
// group cg = l&7). Per 8 edges: 1 per-lane ccv load + 2 uint4 gathers.
#define UNPK_FMA(Q, A0, A1, A2, A3, A4, A5, A6, A7, V) \
  A0 += (V) * lof(Q.x); A1 += (V) * hif(Q.x); \
  A2 += (V) * lof(Q.y); A3 += (V) * hif(Q.y); \
  A4 += (V) * lof(Q.z); A5 += (V) * hif(Q.z); \
  A6 += (V) * lof(Q.w); A7 += (V) * hif(Q.w);

#define RED3(A) { A += __shfl_xor(A, 8); A += __shfl_xor(A, 16); A += __shfl_xor(A, 32); }

template <int BFOUT>
__global__ __launch_bounds__(256) void k_spmm(const unsigned short* __restrict__ src, void* __restrict__ dstv,
                                              const int* __restrict__ rowptr, const int* __restrict__ deg,
                                              const int2* __restrict__ ccv) {
  int n = (blockIdx.x * 256 + threadIdx.x) >> 6;
  int lane = threadIdx.x & 63;
  if (n >= N_NODES) return;
  const int g = lane >> 3;
  const int cg = lane & 7;
  const unsigned short* s0 = src;
  const unsigned short* s1 = src + (size_t)N_NODES * N_C;
  int r0 = rowptr[n];
  int end = r0 + deg[n];
  float a00 = 0, a01 = 0, a02 = 0, a03 = 0, a04 = 0, a05 = 0, a06 = 0, a07 = 0;
  float a10 = 0, a11 = 0, a12 = 0, a13 = 0, a14 = 0, a15 = 0, a16 = 0, a17 = 0;
#pragma unroll 2
  for (int i = r0; i < end; i += 8) {
    int idx = i + g;
    bool ok = idx < end;
    int2 pe = ccv[ok ? idx : (end - 1)];
    float val = ok ? __int_as_float(pe.y) : 0.0f;
    size_t off = (size_t)pe.x * N_C + cg * 8;  // ushort units; 16B aligned
    uint4 q0 = *(const uint4*)(s0 + off);
    uint4 q1 = *(const uint4*)(s1 + off);
    UNPK_FMA(q0, a00, a01, a02, a03, a04, a05, a06, a07, val)
    UNPK_FMA(q1, a10, a11, a12, a13, a14, a15, a16, a17, val)
  }
  RED3(a00) RED3(a01) RED3(a02) RED3(a03) RED3(a04) RED3(a05) RED3(a06) RED3(a07)
  RED3(a10) RED3(a11) RED3(a12) RED3(a13) RED3(a14) RED3(a15) RED3(a16) RED3(a17)
  if (BFOUT) {
    unsigned short* d = (unsigned short*)dstv;
    if (g == 0) {
      uint4 o;
      o.x = (unsigned)f2bf(a00) | ((unsigned)f2bf(a01) << 16);
      o.y = (unsigned)f2bf(a02) | ((unsigned)f2bf(a03) << 16);
      o.z = (unsigned)f2bf(a04) | ((unsigned)f2bf(a05) << 16);
      o.w = (unsigned)f2bf(a06) | ((unsigned)f2bf(a07) << 16);
      *(uint4*)(d + (size_t)n * N_C + cg * 8) = o;
    } else if (g == 1) {
      uint4 o;
      o.x = (unsigned)f2bf(a10) | ((unsigned)f2bf(a11) << 16);
      o.y = (unsigned)f2bf(a12) | ((unsigned)f2bf(a13) << 16);
      o.z = (unsigned)f2bf(a14) | ((unsigned)f2bf(a15) << 16);
      o.w = (unsigned)f2bf(a16) | ((unsigned)f2bf(a17) << 16);
      *(uint4*)(d + ((size_t)N_NODES + n) * N_C + cg * 8) = o;
    }
  } else {
    float* d = (float*)dstv;
    if (g == 0) {
      *(float4*)(d + (size_t)n * N_C + cg * 8) = make_float4(a00, a01, a02, a03);
      *(float4*)(d + (size_t)n * N_C + cg * 8 + 4) = make_float4(a04, a05, a06, a07);
    } else if (g == 1) {
      *(float4*)(d + ((size_t)N_NODES + n) * N_C + cg * 8) = make_float4(a10, a11, a12, a13);
      *(float4*)(d + ((size_t)N_NODES + n) * N_C + cg * 8 + 4) = make_float4(a14, a15, a16, a17);
    }
  }
}

// ---------------- MFMA GEMM: out = [x|Tx1|Z] @ [W0-W2; W1; 2W2] + bias -------
// K=192 = 6 ktiles of 32; B fragments packed bf16 in LDS in fragment order
// (lane l, elem j -> B[(l>>4)*8+j][l&15]); A frags are 16B row loads (x, Tx1
// bf16 direct; Z fp32 -> cvt). C/D: col=lane&15, row=(lane>>4)*4+reg (m89).
// In-place Z: each wave reads ONLY its own 16 rows, then stores them; clamped
// tail rows are loaded-but-never-stored.
__global__ __launch_bounds__(256) void k_gemm(const unsigned short* __restrict__ xb,
                                              const unsigned short* __restrict__ t1h,
                                              const float* __restrict__ w,
                                              const float* __restrict__ bias,
                                              float* out) {
  __shared__ unsigned short bp[6 * 4 * 64 * 8];  // 24KB packed B fragments
  const int t = threadIdx.x;
  for (int idx = t; idx < 1536; idx += 256) {
    int kt = idx >> 8;                 // ktile 0..5
    int rem = idx & 255;
    int c = rem >> 6;                  // coltile 0..3
    int l = rem & 63;                  // frag lane
    int ch = kt >> 1;                  // channel 0..2
    int kbase = (kt & 1) * 32 + (l >> 4) * 8;
    int n = c * 16 + (l & 15);
    unsigned short* dst = &bp[idx * 8];
#pragma unroll
    for (int j = 0; j < 8; ++j) {
      int k = kbase + j;
      float v;
      if (ch == 0)      v = w[k * 64 + n] - w[8192 + k * 64 + n];
      else if (ch == 1) v = w[4096 + k * 64 + n];
      else              v = 2.0f * w[8192 + k * 64 + n];
      dst[j] = f2bf(v);
    }
  }
  __syncthreads();

  const int wid = t >> 6;
  const int lane = t & 63;
  const size_t base = (size_t)blockIdx.x * 64 + (size_t)wid * 16;  // wave's rows
  const int arow = lane & 15;
  const int ko = (lane >> 4) * 8;
  size_t row = base + arow;
  if (row > (size_t)(BN_ROWS - 1)) row = BN_ROWS - 1;  // clamped loads only

  const unsigned short* xp = xb + row * 64 + ko;
  const unsigned short* tp = t1h + row * 64 + ko;
  const float* zp = out + row * 64 + ko;
  short8 ax0 = *(const short8*)(xp);
  short8 ax1 = *(const short8*)(xp + 32);
  short8 at0 = *(const short8*)(tp);
  short8 at1 = *(const short8*)(tp + 32);
  float4 z00 = *(const float4*)(zp);
  float4 z01 = *(const float4*)(zp + 4);
  float4 z10 = *(const float4*)(zp + 32);
  float4 z11 = *(const float4*)(zp + 36);
  short8 az0, az1;
  az0[0] = (short)f2bf(z00.x); az0[1] = (short)f2bf(z00.y);
  az0[2] = (short)f2bf(z00.z); az0[3] = (short)f2bf(z00.w);
  az0[4] = (short)f2bf(z01.x); az0[5] = (short)f2bf(z01.y);
  az0[6] = (short)f2bf(z01.z); az0[7] = (short)f2bf(z01.w);
  az1[0] = (short)f2bf(z10.x); az1[1] = (short)f2bf(z10.y);
  az1[2] = (short)f2bf(z10.z); az1[3] = (short)f2bf(z10.w);
  az1[4] = (short)f2bf(z11.x); az1[5] = (short)f2bf(z11.y);
  az1[6] = (short)f2bf(z11.z); az1[7] = (short)f2bf(z11.w);

  const int col = lane & 15;
  const int rgrp = lane >> 4;

#pragma unroll
  for (int c = 0; c < 4; ++c) {
    const unsigned short* bb = &bp[(size_t)c * 64 * 8];
    short8 b0 = *(const short8*)(bb + (0 * 4 * 64 + lane) * 8);
    short8 b1 = *(const short8*)(bb + (1 * 4 * 64 + lane) * 8);
    short8 b2 = *(const short8*)(bb + (2 * 4 * 64 + lane) * 8);
    short8 b3 = *(const short8*)(bb + (3 * 4 * 64 + lane) * 8);
    short8 b4 = *(const short8*)(bb + (4 * 4 * 64 + lane) * 8);
    short8 b5 = *(const short8*)(bb + (5 * 4 * 64 + lane) * 8);
    f32x4 acc = {0.f, 0.f, 0.f, 0.f};
    acc = __builtin_amdgcn_mfma_f32_16x16x32_bf16(ax0, b0, acc, 0, 0, 0);
    acc = __builtin_amdgcn_mfma_f32_16x16x32_bf16(ax1, b1, acc, 0, 0, 0);
    acc = __builtin_amdgcn_mfma_f32_16x16x32_bf16(at0, b2, acc, 0, 0, 0);
    acc = __builtin_amdgcn_mfma_f32_16x16x32_bf16(at1, b3, acc, 0, 0, 0);
    acc = __builtin_amdgcn_mfma_f32_16x16x32_bf16(az0, b4, acc, 0, 0, 0);
    acc = __builtin_amdgcn_mfma_f32_16x16x32_bf16(az1, b5, acc, 0, 0, 0);
    const float bcol = bias[c * 16 + col];
#pragma unroll
    for (int j = 0; j < 4; ++j) {
      size_t r = base + (size_t)(rgrp * 4 + j);
      if (r < BN_ROWS) out[r * 64 + c * 16 + col] = acc[j] + bcol;
    }
  }
}

extern "C" void kernel_launch(void* const* d_in, const int* in_sizes, int n_in,
                              void* d_out, int out_size, void* d_ws, size_t ws_size,
                              hipStream_t stream) {
  const float* x = (const float*)d_in[0];
  const int* ei = (const int*)d_in[1];        // [2, E] int32
  const float* ew = (const float*)d_in[2];
  const float* w = (const float*)d_in[3];     // [3,64,64]
  const float* bias = (const float*)d_in[4];  // [64]
  float* out = (float*)d_out;

  // workspace layout (4-byte units)
  int* ws32 = (int*)d_ws;
  const size_t NA = 50048;  // padded N (16B-alignment preserved)
  int* deg = ws32;                          // NA ints
  int* bsum = ws32 + NA;                    // small arrays share old cursor region
  int* stageBase = bsum + 256;
  int* stageCur = bsum + 512;
  float* dis = (float*)(ws32 + 2 * NA);
  int* rowptr = (int*)(dis + NA);
  int2* ccv = (int2*)(rowptr + NA);                                    // 2*E ints
  unsigned short* xb = (unsigned short*)(rowptr + NA + 2 * N_EDGES);   // BN_ROWS*64 bf16
  unsigned short* t1h = xb + (size_t)BN_ROWS * N_C;                    // BN_ROWS*64 bf16
  unsigned long long* stage = (unsigned long long*)t1h;                // staging aliases t1h (free until spmm1)
  const size_t NEED = ((size_t)(4 * NA + 2 * N_EDGES) + (size_t)BN_ROWS * N_C) * 4;
  if (ws_size < NEED) return;  // clean fail instead of corruption

  hipMemsetAsync(deg, 0, N_NODES * sizeof(int), stream);
  k_cvt<<<(BN_ROWS * 16 + 255) / 256, 256, 0, stream>>>(x, xb);
  k_deg<<<(N_EDGES + 255) / 256, 256, 0, stream>>>(ei, deg);
  k_bsum<<<NBKT, 256, 0, stream>>>(deg, dis, bsum);
  k_scanb<<<1, 256, 0, stream>>>(bsum, stageBase, stageCur);
  k_part<<<NBKT, 256, 0, stream>>>(ei, ew, dis, stageCur, stage);
  k_build<<<NBKT, 256, 0, stream>>>(deg, stageBase, stage, rowptr, ccv);
  // Tx1 = L x   (bf16 out, both batches per wave)
  k_spmm<1><<<(N_NODES * 64 + 255) / 256, 256, 0, stream>>>(xb, t1h, rowptr, deg, ccv);
  // Z = L Tx1   (fp32, into d_out, both batches per wave)
  k_spmm<0><<<(N_NODES * 64 + 255) / 256, 256, 0, stream>>>(t1h, out, rowptr, deg, ccv);
  // out = [x|Tx1|Z] @ [W0-W2; W1; 2W2] + bias  (MFMA, in-place over Z)
  k_gemm<<<(BN_ROWS + 63) / 64, 256, 0, stream>>>(xb, t1h, w, bias, out);
}

// Round 10
// 291.788 us; speedup vs baseline: 1.4715x; 1.4715x over previous
//
#include <hip/hip_runtime.h>

#define N_NODES 50000
#define N_EDGES 800000
#define N_B 2
#define N_C 64
#define BN_ROWS (N_B * N_NODES)
#define FILL_PHASES 4
#define PHASE_ROWS ((N_NODES + FILL_PHASES - 1) / FILL_PHASES)

typedef __attribute__((ext_vector_type(8))) short short8;   // 8 bf16 = 4 VGPR
typedef __attribute__((ext_vector_type(4))) float f32x4;    // MFMA accum

__device__ inline unsigned short f2bf(float f) {
  unsigned int u = __float_as_uint(f);
  return (unsigned short)((u + 0x7fffu + ((u >> 16) & 1u)) >> 16);  // RNE
}
__device__ inline float bf2f(unsigned short h) { return __uint_as_float(((unsigned int)h) << 16); }
__device__ inline float lof(unsigned int u) { return __uint_as_float(u << 16); }
__device__ inline float hif(unsigned int u) { return __uint_as_float(u & 0xffff0000u); }

// ---------------- degree count (non-self-loop edges per source row) ----------
// deg region is 200KB -> L2-resident, atomics coalesce fine (not in top-5).
__global__ __launch_bounds__(256) void k_deg(const int* __restrict__ ei, int* __restrict__ deg) {
  int e = blockIdx.x * 256 + threadIdx.x;
  if (e >= N_EDGES) return;
  int r = ei[e];
  int c = ei[N_EDGES + e];
  if (r != c) atomicAdd(&deg[r], 1);
}

// ---------------- segment allocator: per-wave prefix + 1 atomic per wave -----
__global__ __launch_bounds__(256) void k_offsets(const int* __restrict__ deg, int* __restrict__ counter,
                                                 int* __restrict__ rowptr, int* __restrict__ cursor,
                                                 float* __restrict__ dis) {
  int n = blockIdx.x * 256 + threadIdx.x;
  int lane = threadIdx.x & 63;
  int d = (n < N_NODES) ? deg[n] : 0;
  int pre = d;
#pragma unroll
  for (int off = 1; off < 64; off <<= 1) {
    int v = __shfl_up(pre, off);
    if (lane >= off) pre += v;
  }
  int waveTotal = __shfl(pre, 63);
  int wbase = 0;
  if (lane == 63) wbase = atomicAdd(counter, waveTotal);
  wbase = __shfl(wbase, 63);
  if (n < N_NODES) {
    int off0 = wbase + pre - d;
    rowptr[n] = off0;
    cursor[n] = off0;
    dis[n] = d > 0 ? rsqrtf((float)d) : 0.0f;
  }
}

// ---------------- fill CSR, row-range phased ---------------------------------
// Round-8: single-pass random 8B scatters over the 6.4MB ccv region thrashed
// the 4MB per-XCD L2 -> every line evicted between its ~8 writes -> 52MB of
// full-line writebacks (46us). Round-9's LDS partitioner killed parallelism
// (196 blocks, 7% occ, 199us) -> reverted. This version keeps the simple
// full-grid scatter but runs 4 sequential phases over row ranges: active ccv
// window = 1.6MB << 4MB L2, writes coalesce in-cache, lines write back once.
// Costs one extra ei/ew stream per phase (~10MB seq reads, full BW).
__global__ __launch_bounds__(256) void k_fill(const int* __restrict__ ei, const float* __restrict__ ew,
                                              const float* __restrict__ dis, int* __restrict__ cursor,
                                              int2* __restrict__ ccv, int rlo, int rhi) {
  int e = blockIdx.x * 256 + threadIdx.x;
  if (e >= N_EDGES) return;
  int r = ei[e];
  if (r < rlo || r >= rhi) return;
  int c = ei[N_EDGES + e];
  if (r == c) return;
  float v = -dis[r] * ew[e] * dis[c];
  int pos = atomicAdd(&cursor[r], 1);
  ccv[pos] = make_int2(c, __float_as_int(v));
}

// ---------------- x (fp32) -> bf16 copy --------------------------------------
__global__ __launch_bounds__(256) void k_cvt(const float* __restrict__ x, unsigned short* __restrict__ xb) {
  int i = blockIdx.x * 256 + threadIdx.x;  // float4-quad index
  if (i >= BN_ROWS * 16) return;
  float4 v = ((const float4*)x)[i];
  ushort4 h;
  h.x = f2bf(v.x); h.y = f2bf(v.y); h.z = f2bf(v.z); h.w = f2bf(v.w);
  ((ushort4*)xb)[i] = h;
}

// ---------------- SPMM: dst[b,n,:] = sum_e lap_e * src[b,col_e,:] ------------
// One wave per NODE, BOTH batches. lane = (edge-slot g = l>>3) x (channel
// group cg = l&7). Per 8 edges: 1 per-lane ccv load + 2 uint4 gathers.
#define UNPK_FMA(Q, A0, A1, A2, A3, A4, A5, A6, A7, V) \
  A0 += (V) * lof(Q.x); A1 += (V) * hif(Q.x); \
  A2 += (V) * lof(Q.y); A3 += (V) * hif(Q.y); \
  A4 += (V) * lof(Q.z); A5 += (V) * hif(Q.z); \
  A6 += (V) * lof(Q.w); A7 += (V) * hif(Q.w);

#define RED3(A) { A += __shfl_xor(A, 8); A += __shfl_xor(A, 16); A += __shfl_xor(A, 32); }

template <int BFOUT>
__global__ __launch_bounds__(256) void k_spmm(const unsigned short* __restrict__ src, void* __restrict__ dstv,
                                              const int* __restrict__ rowptr, const int* __restrict__ deg,
                                              const int2* __restrict__ ccv) {
  int n = (blockIdx.x * 256 + threadIdx.x) >> 6;
  int lane = threadIdx.x & 63;
  if (n >= N_NODES) return;
  const int g = lane >> 3;
  const int cg = lane & 7;
  const unsigned short* s0 = src;
  const unsigned short* s1 = src + (size_t)N_NODES * N_C;
  int r0 = rowptr[n];
  int end = r0 + deg[n];
  float a00 = 0, a01 = 0, a02 = 0, a03 = 0, a04 = 0, a05 = 0, a06 = 0, a07 = 0;
  float a10 = 0, a11 = 0, a12 = 0, a13 = 0, a14 = 0, a15 = 0, a16 = 0, a17 = 0;
#pragma unroll 2
  for (int i = r0; i < end; i += 8) {
    int idx = i + g;
    bool ok = idx < end;
    int2 pe = ccv[ok ? idx : (end - 1)];
    float val = ok ? __int_as_float(pe.y) : 0.0f;
    size_t off = (size_t)pe.x * N_C + cg * 8;  // ushort units; 16B aligned
    uint4 q0 = *(const uint4*)(s0 + off);
    uint4 q1 = *(const uint4*)(s1 + off);
    UNPK_FMA(q0, a00, a01, a02, a03, a04, a05, a06, a07, val)
    UNPK_FMA(q1, a10, a11, a12, a13, a14, a15, a16, a17, val)
  }
  RED3(a00) RED3(a01) RED3(a02) RED3(a03) RED3(a04) RED3(a05) RED3(a06) RED3(a07)
  RED3(a10) RED3(a11) RED3(a12) RED3(a13) RED3(a14) RED3(a15) RED3(a16) RED3(a17)
  if (BFOUT) {
    unsigned short* d = (unsigned short*)dstv;
    if (g == 0) {
      uint4 o;
      o.x = (unsigned)f2bf(a00) | ((unsigned)f2bf(a01) << 16);
      o.y = (unsigned)f2bf(a02) | ((unsigned)f2bf(a03) << 16);
      o.z = (unsigned)f2bf(a04) | ((unsigned)f2bf(a05) << 16);
      o.w = (unsigned)f2bf(a06) | ((unsigned)f2bf(a07) << 16);
      *(uint4*)(d + (size_t)n * N_C + cg * 8) = o;
    } else if (g == 1) {
      uint4 o;
      o.x = (unsigned)f2bf(a10) | ((unsigned)f2bf(a11) << 16);
      o.y = (unsigned)f2bf(a12) | ((unsigned)f2bf(a13) << 16);
      o.z = (unsigned)f2bf(a14) | ((unsigned)f2bf(a15) << 16);
      o.w = (unsigned)f2bf(a16) | ((unsigned)f2bf(a17) << 16);
      *(uint4*)(d + ((size_t)N_NODES + n) * N_C + cg * 8) = o;
    }
  } else {
    float* d = (float*)dstv;
    if (g == 0) {
      *(float4*)(d + (size_t)n * N_C + cg * 8) = make_float4(a00, a01, a02, a03);
      *(float4*)(d + (size_t)n * N_C + cg * 8 + 4) = make_float4(a04, a05, a06, a07);
    } else if (g == 1) {
      *(float4*)(d + ((size_t)N_NODES + n) * N_C + cg * 8) = make_float4(a10, a11, a12, a13);
      *(float4*)(d + ((size_t)N_NODES + n) * N_C + cg * 8 + 4) = make_float4(a14, a15, a16, a17);
    }
  }
}

// ---------------- MFMA GEMM: out = [x|Tx1|Z] @ [W0-W2; W1; 2W2] + bias -------
// K=192 = 6 ktiles of 32; B fragments packed bf16 in LDS in fragment order
// (lane l, elem j -> B[(l>>4)*8+j][l&15]); A frags are 16B row loads (x, Tx1
// bf16 direct; Z fp32 -> cvt). C/D: col=lane&15, row=(lane>>4)*4+reg (m89).
// In-place Z: each wave reads ONLY its own 16 rows, then stores them; clamped
// tail rows are loaded-but-never-stored.
__global__ __launch_bounds__(256) void k_gemm(const unsigned short* __restrict__ xb,
                                              const unsigned short* __restrict__ t1h,
                                              const float* __restrict__ w,
                                              const float* __restrict__ bias,
                                              float* out) {
  __shared__ unsigned short bp[6 * 4 * 64 * 8];  // 24KB packed B fragments
  const int t = threadIdx.x;
  for (int idx = t; idx < 1536; idx += 256) {
    int kt = idx >> 8;                 // ktile 0..5
    int rem = idx & 255;
    int c = rem >> 6;                  // coltile 0..3
    int l = rem & 63;                  // frag lane
    int ch = kt >> 1;                  // channel 0..2
    int kbase = (kt & 1) * 32 + (l >> 4) * 8;
    int n = c * 16 + (l & 15);
    unsigned short* dst = &bp[idx * 8];
#pragma unroll
    for (int j = 0; j < 8; ++j) {
      int k = kbase + j;
      float v;
      if (ch == 0)      v = w[k * 64 + n] - w[8192 + k * 64 + n];
      else if (ch == 1) v = w[4096 + k * 64 + n];
      else              v = 2.0f * w[8192 + k * 64 + n];
      dst[j] = f2bf(v);
    }
  }
  __syncthreads();

  const int wid = t >> 6;
  const int lane = t & 63;
  const size_t base = (size_t)blockIdx.x * 64 + (size_t)wid * 16;  // wave's rows
  const int arow = lane & 15;
  const int ko = (lane >> 4) * 8;
  size_t row = base + arow;
  if (row > (size_t)(BN_ROWS - 1)) row = BN_ROWS - 1;  // clamped loads only

  const unsigned short* xp = xb + row * 64 + ko;
  const unsigned short* tp = t1h + row * 64 + ko;
  const float* zp = out + row * 64 + ko;
  short8 ax0 = *(const short8*)(xp);
  short8 ax1 = *(const short8*)(xp + 32);
  short8 at0 = *(const short8*)(tp);
  short8 at1 = *(const short8*)(tp + 32);
  float4 z00 = *(const float4*)(zp);
  float4 z01 = *(const float4*)(zp + 4);
  float4 z10 = *(const float4*)(zp + 32);
  float4 z11 = *(const float4*)(zp + 36);
  short8 az0, az1;
  az0[0] = (short)f2bf(z00.x); az0[1] = (short)f2bf(z00.y);
  az0[2] = (short)f2bf(z00.z); az0[3] = (short)f2bf(z00.w);
  az0[4] = (short)f2bf(z01.x); az0[5] = (short)f2bf(z01.y);
  az0[6] = (short)f2bf(z01.z); az0[7] = (short)f2bf(z01.w);
  az1[0] = (short)f2bf(z10.x); az1[1] = (short)f2bf(z10.y);
  az1[2] = (short)f2bf(z10.z); az1[3] = (short)f2bf(z10.w);
  az1[4] = (short)f2bf(z11.x); az1[5] = (short)f2bf(z11.y);
  az1[6] = (short)f2bf(z11.z); az1[7] = (short)f2bf(z11.w);

  const int col = lane & 15;
  const int rgrp = lane >> 4;

#pragma unroll
  for (int c = 0; c < 4; ++c) {
    const unsigned short* bb = &bp[(size_t)c * 64 * 8];
    short8 b0 = *(const short8*)(bb + (0 * 4 * 64 + lane) * 8);
    short8 b1 = *(const short8*)(bb + (1 * 4 * 64 + lane) * 8);
    short8 b2 = *(const short8*)(bb + (2 * 4 * 64 + lane) * 8);
    short8 b3 = *(const short8*)(bb + (3 * 4 * 64 + lane) * 8);
    short8 b4 = *(const short8*)(bb + (4 * 4 * 64 + lane) * 8);
    short8 b5 = *(const short8*)(bb + (5 * 4 * 64 + lane) * 8);
    f32x4 acc = {0.f, 0.f, 0.f, 0.f};
    acc = __builtin_amdgcn_mfma_f32_16x16x32_bf16(ax0, b0, acc, 0, 0, 0);
    acc = __builtin_amdgcn_mfma_f32_16x16x32_bf16(ax1, b1, acc, 0, 0, 0);
    acc = __builtin_amdgcn_mfma_f32_16x16x32_bf16(at0, b2, acc, 0, 0, 0);
    acc = __builtin_amdgcn_mfma_f32_16x16x32_bf16(at1, b3, acc, 0, 0, 0);
    acc = __builtin_amdgcn_mfma_f32_16x16x32_bf16(az0, b4, acc, 0, 0, 0);
    acc = __builtin_amdgcn_mfma_f32_16x16x32_bf16(az1, b5, acc, 0, 0, 0);
    const float bcol = bias[c * 16 + col];
#pragma unroll
    for (int j = 0; j < 4; ++j) {
      size_t r = base + (size_t)(rgrp * 4 + j);
      if (r < BN_ROWS) out[r * 64 + c * 16 + col] = acc[j] + bcol;
    }
  }
}

extern "C" void kernel_launch(void* const* d_in, const int* in_sizes, int n_in,
                              void* d_out, int out_size, void* d_ws, size_t ws_size,
                              hipStream_t stream) {
  const float* x = (const float*)d_in[0];
  const int* ei = (const int*)d_in[1];        // [2, E] int32
  const float* ew = (const float*)d_in[2];
  const float* w = (const float*)d_in[3];     // [3,64,64]
  const float* bias = (const float*)d_in[4];  // [64]
  float* out = (float*)d_out;

  // workspace layout (4-byte units)
  int* ws32 = (int*)d_ws;
  const size_t NA = 50048;  // padded N (16B-alignment preserved)
  int* deg = ws32;                          // [0..N) degrees, [N] = counter
  int* counter = deg + N_NODES;
  int* cursor = ws32 + NA;
  float* dis = (float*)(cursor + NA);
  int* rowptr = (int*)(dis + NA);
  int2* ccv = (int2*)(rowptr + NA);                                    // 2*E ints
  unsigned short* xb = (unsigned short*)(rowptr + NA + 2 * N_EDGES);   // BN_ROWS*64 bf16
  unsigned short* t1h = xb + (size_t)BN_ROWS * N_C;                    // BN_ROWS*64 bf16
  const size_t NEED = ((size_t)(4 * NA + 2 * N_EDGES) + (size_t)BN_ROWS * N_C) * 4;
  if (ws_size < NEED) return;  // clean fail instead of corruption

  hipMemsetAsync(deg, 0, (N_NODES + 1) * sizeof(int), stream);  // deg + counter
  k_cvt<<<(BN_ROWS * 16 + 255) / 256, 256, 0, stream>>>(x, xb);
  k_deg<<<(N_EDGES + 255) / 256, 256, 0, stream>>>(ei, deg);
  k_offsets<<<(N_NODES + 255) / 256, 256, 0, stream>>>(deg, counter, rowptr, cursor, dis);
  // phased CSR fill: active ccv window ~1.6MB -> L2-resident, writes coalesce
  for (int p = 0; p < FILL_PHASES; ++p) {
    k_fill<<<(N_EDGES + 255) / 256, 256, 0, stream>>>(ei, ew, dis, cursor, ccv,
                                                      p * PHASE_ROWS, (p + 1) * PHASE_ROWS);
  }
  // Tx1 = L x   (bf16 out, both batches per wave)
  k_spmm<1><<<(N_NODES * 64 + 255) / 256, 256, 0, stream>>>(xb, t1h, rowptr, deg, ccv);
  // Z = L Tx1   (fp32, into d_out, both batches per wave)
  k_spmm<0><<<(N_NODES * 64 + 255) / 256, 256, 0, stream>>>(t1h, out, rowptr, deg, ccv);
  // out = [x|Tx1|Z] @ [W0-W2; W1; 2W2] + bias  (MFMA, in-place over Z)
  k_gemm<<<(BN_ROWS + 63) / 64, 256, 0, stream>>>(xb, t1h, w, bias, out);
}

// Round 12
// 264.290 us; speedup vs baseline: 1.6246x; 1.1040x over previous
//
#include <hip/hip_runtime.h>

#define N_NODES 50000
#define N_EDGES 800000
#define N_B 2
#define N_C 64
#define BN_ROWS (N_B * N_NODES)

typedef __attribute__((ext_vector_type(8))) short short8;   // 8 bf16 = 4 VGPR
typedef __attribute__((ext_vector_type(4))) float f32x4;    // MFMA accum

__device__ inline unsigned short f2bf(float f) {
  unsigned int u = __float_as_uint(f);
  return (unsigned short)((u + 0x7fffu + ((u >> 16) & 1u)) >> 16);  // RNE
}
__device__ inline float bf2f(unsigned short h) { return __uint_as_float(((unsigned int)h) << 16); }
__device__ inline float lof(unsigned int u) { return __uint_as_float(u << 16); }
__device__ inline float hif(unsigned int u) { return __uint_as_float(u & 0xffff0000u); }

__device__ inline short8 pk8(float4 a, float4 b) {
  short8 r;
  r[0] = (short)f2bf(a.x); r[1] = (short)f2bf(a.y); r[2] = (short)f2bf(a.z); r[3] = (short)f2bf(a.w);
  r[4] = (short)f2bf(b.x); r[5] = (short)f2bf(b.y); r[6] = (short)f2bf(b.z); r[7] = (short)f2bf(b.w);
  return r;
}

// ---------------- degree count (non-self-loop edges per source row) ----------
__global__ __launch_bounds__(256) void k_deg(const int* __restrict__ ei, int* __restrict__ deg) {
  int e = blockIdx.x * 256 + threadIdx.x;
  if (e >= N_EDGES) return;
  int r = ei[e];
  int c = ei[N_EDGES + e];
  if (r != c) atomicAdd(&deg[r], 1);
}

// ---------------- segment allocator: per-wave prefix + 1 atomic per wave -----
__global__ __launch_bounds__(256) void k_offsets(const int* __restrict__ deg, int* __restrict__ counter,
                                                 int* __restrict__ rowptr, int* __restrict__ cursor,
                                                 float* __restrict__ dis) {
  int n = blockIdx.x * 256 + threadIdx.x;
  int lane = threadIdx.x & 63;
  int d = (n < N_NODES) ? deg[n] : 0;
  int pre = d;
#pragma unroll
  for (int off = 1; off < 64; off <<= 1) {
    int v = __shfl_up(pre, off);
    if (lane >= off) pre += v;
  }
  int waveTotal = __shfl(pre, 63);
  int wbase = 0;
  if (lane == 63) wbase = atomicAdd(counter, waveTotal);
  wbase = __shfl(wbase, 63);
  if (n < N_NODES) {
    int off0 = wbase + pre - d;
    rowptr[n] = off0;
    cursor[n] = off0;
    dis[n] = d > 0 ? rsqrtf((float)d) : 0.0f;
  }
}

// ---------------- fill CSR (single-phase; round-10 showed phasing was net-) --
__global__ __launch_bounds__(256) void k_fill(const int* __restrict__ ei, const float* __restrict__ ew,
                                              const float* __restrict__ dis, int* __restrict__ cursor,
                                              int2* __restrict__ ccv) {
  int e = blockIdx.x * 256 + threadIdx.x;
  if (e >= N_EDGES) return;
  int r = ei[e];
  int c = ei[N_EDGES + e];
  if (r == c) return;
  float v = -dis[r] * ew[e] * dis[c];
  int pos = atomicAdd(&cursor[r], 1);
  ccv[pos] = make_int2(c, __float_as_int(v));
}

// ---------------- one-time weight pack into B-fragment order (global) --------
// Round-10 diagnosis: packing inside k_gemm cost every block ~12K strided
// scalar w-loads + 8-way-conflicted ds_write_b16 (1.8M conflicts) + barrier
// -> 49.6us with ALL pipes idle. Hoisted here: runs once on 1536 threads.
// Element offset = kt*2048 + c*512 + l*8 (kt=ktile 0..5, c=coltile, l=lane).
__global__ __launch_bounds__(256) void k_pack(const float* __restrict__ w, unsigned short* __restrict__ bpg) {
  int idx = blockIdx.x * 256 + threadIdx.x;  // 0..1535
  if (idx >= 1536) return;
  int kt = idx >> 8;
  int rem = idx & 255;
  int c = rem >> 6;
  int l = rem & 63;
  int ch = kt >> 1;
  int kbase = (kt & 1) * 32 + (l >> 4) * 8;
  int n = c * 16 + (l & 15);
  unsigned short* dst = &bpg[idx * 8];
#pragma unroll
  for (int j = 0; j < 8; ++j) {
    int k = kbase + j;
    float v;
    if (ch == 0)      v = w[k * 64 + n] - w[8192 + k * 64 + n];
    else if (ch == 1) v = w[4096 + k * 64 + n];
    else              v = 2.0f * w[8192 + k * 64 + n];
    dst[j] = f2bf(v);
  }
}

// ---------------- x (fp32) -> bf16 copy --------------------------------------
__global__ __launch_bounds__(256) void k_cvt(const float* __restrict__ x, unsigned short* __restrict__ xb) {
  int i = blockIdx.x * 256 + threadIdx.x;  // float4-quad index
  if (i >= BN_ROWS * 16) return;
  float4 v = ((const float4*)x)[i];
  ushort4 h;
  h.x = f2bf(v.x); h.y = f2bf(v.y); h.z = f2bf(v.z); h.w = f2bf(v.w);
  ((ushort4*)xb)[i] = h;
}

// ---------------- SPMM: dst[b,n,:] = sum_e lap_e * src[b,col_e,:] ------------
// One wave per NODE, BOTH batches. lane = (edge-slot g = l>>3) x (channel
// group cg = l&7). Per 8 edges: 1 per-lane ccv load + 2 uint4 gathers.
#define UNPK_FMA(Q, A0, A1, A2, A3, A4, A5, A6, A7, V) \
  A0 += (V) * lof(Q.x); A1 += (V) * hif(Q.x); \
  A2 += (V) * lof(Q.y); A3 += (V) * hif(Q.y); \
  A4 += (V) * lof(Q.z); A5 += (V) * hif(Q.z); \
  A6 += (V) * lof(Q.w); A7 += (V) * hif(Q.w);

#define RED3(A) { A += __shfl_xor(A, 8); A += __shfl_xor(A, 16); A += __shfl_xor(A, 32); }

template <int BFOUT>
__global__ __launch_bounds__(256) void k_spmm(const unsigned short* __restrict__ src, void* __restrict__ dstv,
                                              const int* __restrict__ rowptr, const int* __restrict__ deg,
                                              const int2* __restrict__ ccv) {
  int n = (blockIdx.x * 256 + threadIdx.x) >> 6;
  int lane = threadIdx.x & 63;
  if (n >= N_NODES) return;
  const int g = lane >> 3;
  const int cg = lane & 7;
  const unsigned short* s0 = src;
  const unsigned short* s1 = src + (size_t)N_NODES * N_C;
  int r0 = rowptr[n];
  int end = r0 + deg[n];
  float a00 = 0, a01 = 0, a02 = 0, a03 = 0, a04 = 0, a05 = 0, a06 = 0, a07 = 0;
  float a10 = 0, a11 = 0, a12 = 0, a13 = 0, a14 = 0, a15 = 0, a16 = 0, a17 = 0;
#pragma unroll 2
  for (int i = r0; i < end; i += 8) {
    int idx = i + g;
    bool ok = idx < end;
    int2 pe = ccv[ok ? idx : (end - 1)];
    float val = ok ? __int_as_float(pe.y) : 0.0f;
    size_t off = (size_t)pe.x * N_C + cg * 8;  // ushort units; 16B aligned
    uint4 q0 = *(const uint4*)(s0 + off);
    uint4 q1 = *(const uint4*)(s1 + off);
    UNPK_FMA(q0, a00, a01, a02, a03, a04, a05, a06, a07, val)
    UNPK_FMA(q1, a10, a11, a12, a13, a14, a15, a16, a17, val)
  }
  RED3(a00) RED3(a01) RED3(a02) RED3(a03) RED3(a04) RED3(a05) RED3(a06) RED3(a07)
  RED3(a10) RED3(a11) RED3(a12) RED3(a13) RED3(a14) RED3(a15) RED3(a16) RED3(a17)
  if (BFOUT) {
    unsigned short* d = (unsigned short*)dstv;
    if (g == 0) {
      uint4 o;
      o.x = (unsigned)f2bf(a00) | ((unsigned)f2bf(a01) << 16);
      o.y = (unsigned)f2bf(a02) | ((unsigned)f2bf(a03) << 16);
      o.z = (unsigned)f2bf(a04) | ((unsigned)f2bf(a05) << 16);
      o.w = (unsigned)f2bf(a06) | ((unsigned)f2bf(a07) << 16);
      *(uint4*)(d + (size_t)n * N_C + cg * 8) = o;
    } else if (g == 1) {
      uint4 o;
      o.x = (unsigned)f2bf(a10) | ((unsigned)f2bf(a11) << 16);
      o.y = (unsigned)f2bf(a12) | ((unsigned)f2bf(a13) << 16);
      o.z = (unsigned)f2bf(a14) | ((unsigned)f2bf(a15) << 16);
      o.w = (unsigned)f2bf(a16) | ((unsigned)f2bf(a17) << 16);
      *(uint4*)(d + ((size_t)N_NODES + n) * N_C + cg * 8) = o;
    }
  } else {
    float* d = (float*)dstv;
    if (g == 0) {
      *(float4*)(d + (size_t)n * N_C + cg * 8) = make_float4(a00, a01, a02, a03);
      *(float4*)(d + (size_t)n * N_C + cg * 8 + 4) = make_float4(a04, a05, a06, a07);
    } else if (g == 1) {
      *(float4*)(d + ((size_t)N_NODES + n) * N_C + cg * 8) = make_float4(a10, a11, a12, a13);
      *(float4*)(d + ((size_t)N_NODES + n) * N_C + cg * 8 + 4) = make_float4(a14, a15, a16, a17);
    }
  }
}

// ---------------- MFMA GEMM: out = [x|Tx1|Z] @ [W0-W2; W1; 2W2] + bias -------
// 128 rows/block (782 blocks); wave owns 32 rows = 2 sub-tiles of 16. Stage:
// 6 coalesced 16B loads/thread from pre-packed global -> conflict-free
// ds_write_b128. Then 16 independent A/Z loads (256B/lane in flight), per
// c-tile one set of B-frag LDS reads feeding two independent 6-MFMA chains.
// In-place Z: all of a wave's loads precede its stores; waves own disjoint
// rows; clamped tail loads are discarded (stores predicated).
__global__ __launch_bounds__(256) void k_gemm(const unsigned short* __restrict__ xb,
                                              const unsigned short* __restrict__ t1h,
                                              const unsigned short* __restrict__ bpg,
                                              const float* __restrict__ bias,
                                              float* out) {
  __shared__ unsigned short bp[12288];  // 24KB packed B fragments
  const int t = threadIdx.x;
#pragma unroll
  for (int i = 0; i < 6; ++i) {
    int idx = i * 256 + t;
    *(uint4*)&bp[idx * 8] = *(const uint4*)&bpg[idx * 8];
  }
  __syncthreads();

  const int wid = t >> 6;
  const int lane = t & 63;
  const size_t wbase = (size_t)blockIdx.x * 128 + (size_t)wid * 32;  // wave's 32 rows
  const int arow = lane & 15;
  const int ko = (lane >> 4) * 8;
  size_t rowA = wbase + arow;
  size_t rowB = wbase + 16 + arow;
  if (rowA > (size_t)(BN_ROWS - 1)) rowA = BN_ROWS - 1;  // clamped loads only
  if (rowB > (size_t)(BN_ROWS - 1)) rowB = BN_ROWS - 1;

  // ---- 16 independent loads (8 per sub-tile), all issued before any store --
  const unsigned short* xpA = xb + rowA * 64 + ko;
  const unsigned short* tpA = t1h + rowA * 64 + ko;
  const float* zpA = out + rowA * 64 + ko;
  const unsigned short* xpB = xb + rowB * 64 + ko;
  const unsigned short* tpB = t1h + rowB * 64 + ko;
  const float* zpB = out + rowB * 64 + ko;
  short8 axA0 = *(const short8*)(xpA);
  short8 axA1 = *(const short8*)(xpA + 32);
  short8 atA0 = *(const short8*)(tpA);
  short8 atA1 = *(const short8*)(tpA + 32);
  float4 zA0 = *(const float4*)(zpA);
  float4 zA1 = *(const float4*)(zpA + 4);
  float4 zA2 = *(const float4*)(zpA + 32);
  float4 zA3 = *(const float4*)(zpA + 36);
  short8 axB0 = *(const short8*)(xpB);
  short8 axB1 = *(const short8*)(xpB + 32);
  short8 atB0 = *(const short8*)(tpB);
  short8 atB1 = *(const short8*)(tpB + 32);
  float4 zB0 = *(const float4*)(zpB);
  float4 zB1 = *(const float4*)(zpB + 4);
  float4 zB2 = *(const float4*)(zpB + 32);
  float4 zB3 = *(const float4*)(zpB + 36);
  short8 azA0 = pk8(zA0, zA1);
  short8 azA1 = pk8(zA2, zA3);
  short8 azB0 = pk8(zB0, zB1);
  short8 azB1 = pk8(zB2, zB3);

  const int col = lane & 15;
  const int rgrp = lane >> 4;

#pragma unroll
  for (int c = 0; c < 4; ++c) {
    const unsigned short* bb = bp + c * 512;
    short8 b0 = *(const short8*)(bb + (0 * 256 + lane) * 8);
    short8 b1 = *(const short8*)(bb + (1 * 256 + lane) * 8);
    short8 b2 = *(const short8*)(bb + (2 * 256 + lane) * 8);
    short8 b3 = *(const short8*)(bb + (3 * 256 + lane) * 8);
    short8 b4 = *(const short8*)(bb + (4 * 256 + lane) * 8);
    short8 b5 = *(const short8*)(bb + (5 * 256 + lane) * 8);
    f32x4 accA = {0.f, 0.f, 0.f, 0.f};
    f32x4 accB = {0.f, 0.f, 0.f, 0.f};
    accA = __builtin_amdgcn_mfma_f32_16x16x32_bf16(axA0, b0, accA, 0, 0, 0);
    accB = __builtin_amdgcn_mfma_f32_16x16x32_bf16(axB0, b0, accB, 0, 0, 0);
    accA = __builtin_amdgcn_mfma_f32_16x16x32_bf16(axA1, b1, accA, 0, 0, 0);
    accB = __builtin_amdgcn_mfma_f32_16x16x32_bf16(axB1, b1, accB, 0, 0, 0);
    accA = __builtin_amdgcn_mfma_f32_16x16x32_bf16(atA0, b2, accA, 0, 0, 0);
    accB = __builtin_amdgcn_mfma_f32_16x16x32_bf16(atB0, b2, accB, 0, 0, 0);
    accA = __builtin_amdgcn_mfma_f32_16x16x32_bf16(atA1, b3, accA, 0, 0, 0);
    accB = __builtin_amdgcn_mfma_f32_16x16x32_bf16(atB1, b3, accB, 0, 0, 0);
    accA = __builtin_amdgcn_mfma_f32_16x16x32_bf16(azA0, b4, accA, 0, 0, 0);
    accB = __builtin_amdgcn_mfma_f32_16x16x32_bf16(azB0, b4, accB, 0, 0, 0);
    accA = __builtin_amdgcn_mfma_f32_16x16x32_bf16(azA1, b5, accA, 0, 0, 0);
    accB = __builtin_amdgcn_mfma_f32_16x16x32_bf16(azB1, b5, accB, 0, 0, 0);
    const float bcol = bias[c * 16 + col];
#pragma unroll
    for (int j = 0; j < 4; ++j) {
      size_t rA = wbase + (size_t)(rgrp * 4 + j);
      size_t rB = wbase + 16 + (size_t)(rgrp * 4 + j);
      if (rA < BN_ROWS) out[rA * 64 + c * 16 + col] = accA[j] + bcol;
      if (rB < BN_ROWS) out[rB * 64 + c * 16 + col] = accB[j] + bcol;
    }
  }
}

extern "C" void kernel_launch(void* const* d_in, const int* in_sizes, int n_in,
                              void* d_out, int out_size, void* d_ws, size_t ws_size,
                              hipStream_t stream) {
  const float* x = (const float*)d_in[0];
  const int* ei = (const int*)d_in[1];        // [2, E] int32
  const float* ew = (const float*)d_in[2];
  const float* w = (const float*)d_in[3];     // [3,64,64]
  const float* bias = (const float*)d_in[4];  // [64]
  float* out = (float*)d_out;

  // workspace layout (4-byte units)
  int* ws32 = (int*)d_ws;
  const size_t NA = 50048;  // padded N (16B-alignment preserved)
  int* deg = ws32;                          // [0..N) degrees, [N] = counter
  int* counter = deg + N_NODES;
  int* cursor = ws32 + NA;                  // free after k_fill -> reused for bpg
  float* dis = (float*)(cursor + NA);
  int* rowptr = (int*)(dis + NA);
  int2* ccv = (int2*)(rowptr + NA);                                    // 2*E ints
  unsigned short* xb = (unsigned short*)(rowptr + NA + 2 * N_EDGES);   // BN_ROWS*64 bf16
  unsigned short* t1h = xb + (size_t)BN_ROWS * N_C;                    // BN_ROWS*64 bf16
  unsigned short* bpg = (unsigned short*)cursor;                       // 24KB, aliases cursor
  const size_t NEED = ((size_t)(4 * NA + 2 * N_EDGES) + (size_t)BN_ROWS * N_C) * 4;
  if (ws_size < NEED) return;  // clean fail instead of corruption

  hipMemsetAsync(deg, 0, (N_NODES + 1) * sizeof(int), stream);  // deg + counter
  k_cvt<<<(BN_ROWS * 16 + 255) / 256, 256, 0, stream>>>(x, xb);
  k_deg<<<(N_EDGES + 255) / 256, 256, 0, stream>>>(ei, deg);
  k_offsets<<<(N_NODES + 255) / 256, 256, 0, stream>>>(deg, counter, rowptr, cursor, dis);
  k_fill<<<(N_EDGES + 255) / 256, 256, 0, stream>>>(ei, ew, dis, cursor, ccv);
  k_pack<<<6, 256, 0, stream>>>(w, bpg);  // cursor dead after k_fill
  // Tx1 = L x   (bf16 out, both batches per wave)
  k_spmm<1><<<(N_NODES * 64 + 255) / 256, 256, 0, stream>>>(xb, t1h, rowptr, deg, ccv);
  // Z = L Tx1   (fp32, into d_out, both batches per wave)
  k_spmm<0><<<(N_NODES * 64 + 255) / 256, 256, 0, stream>>>(t1h, out, rowptr, deg, ccv);
  // out = [x|Tx1|Z] @ [W0-W2; W1; 2W2] + bias  (MFMA, in-place over Z)
  k_gemm<<<(BN_ROWS + 127) / 128, 256, 0, stream>>>(xb, t1h, bpg, bias, out);
}

// Round 13
// 255.217 us; speedup vs baseline: 1.6823x; 1.0356x over previous
//
#include <hip/hip_runtime.h>

#define N_NODES 50000
#define N_EDGES 800000
#define N_B 2
#define N_C 64
#define BN_ROWS (N_B * N_NODES)

typedef __attribute__((ext_vector_type(8))) short short8;   // 8 bf16 = 4 VGPR
typedef __attribute__((ext_vector_type(4))) float f32x4;    // MFMA accum

__device__ inline unsigned short f2bf(float f) {
  unsigned int u = __float_as_uint(f);
  return (unsigned short)((u + 0x7fffu + ((u >> 16) & 1u)) >> 16);  // RNE
}
__device__ inline float bf2f(unsigned short h) { return __uint_as_float(((unsigned int)h) << 16); }
__device__ inline float lof(unsigned int u) { return __uint_as_float(u << 16); }
__device__ inline float hif(unsigned int u) { return __uint_as_float(u & 0xffff0000u); }

// ---------------- degree count (non-self-loop edges per source row) ----------
__global__ __launch_bounds__(256) void k_deg(const int* __restrict__ ei, int* __restrict__ deg) {
  int e = blockIdx.x * 256 + threadIdx.x;
  if (e >= N_EDGES) return;
  int r = ei[e];
  int c = ei[N_EDGES + e];
  if (r != c) atomicAdd(&deg[r], 1);
}

// ---------------- segment allocator: per-wave prefix + 1 atomic per wave -----
__global__ __launch_bounds__(256) void k_offsets(const int* __restrict__ deg, int* __restrict__ counter,
                                                 int* __restrict__ rowptr, int* __restrict__ cursor,
                                                 float* __restrict__ dis) {
  int n = blockIdx.x * 256 + threadIdx.x;
  int lane = threadIdx.x & 63;
  int d = (n < N_NODES) ? deg[n] : 0;
  int pre = d;
#pragma unroll
  for (int off = 1; off < 64; off <<= 1) {
    int v = __shfl_up(pre, off);
    if (lane >= off) pre += v;
  }
  int waveTotal = __shfl(pre, 63);
  int wbase = 0;
  if (lane == 63) wbase = atomicAdd(counter, waveTotal);
  wbase = __shfl(wbase, 63);
  if (n < N_NODES) {
    int off0 = wbase + pre - d;
    rowptr[n] = off0;
    cursor[n] = off0;
    dis[n] = d > 0 ? rsqrtf((float)d) : 0.0f;
  }
}

// ---------------- fill CSR: 4B packed entry (col u16 | val bf16) -------------
// Round-12 diagnosis: 8B random scatters over a 6.4MB region -> 52MB of
// line-granular writebacks (region exceeds per-XCD 4MB L2). 4B entries halve
// the region to 3.2MB (L2-resident per XCD) and double entries/line to 16,
// so in-cache write combining works. val in bf16 (gemm/spmm already consume
// bf16 products; adds ~0.2% rel per edge, absmax budget holds).
__global__ __launch_bounds__(256) void k_fill(const int* __restrict__ ei, const float* __restrict__ ew,
                                              const float* __restrict__ dis, int* __restrict__ cursor,
                                              unsigned int* __restrict__ ccv) {
  int e = blockIdx.x * 256 + threadIdx.x;
  if (e >= N_EDGES) return;
  int r = ei[e];
  int c = ei[N_EDGES + e];
  if (r == c) return;
  float v = -dis[r] * ew[e] * dis[c];
  int pos = atomicAdd(&cursor[r], 1);
  ccv[pos] = (unsigned int)c | ((unsigned int)f2bf(v) << 16);
}

// ---------------- one-time weight pack into B-fragment order (global) --------
// Element offset = kt*2048 + c*512 + l*8 (kt=ktile 0..5, c=coltile, l=lane).
__global__ __launch_bounds__(256) void k_pack(const float* __restrict__ w, unsigned short* __restrict__ bpg) {
  int idx = blockIdx.x * 256 + threadIdx.x;  // 0..1535
  if (idx >= 1536) return;
  int kt = idx >> 8;
  int rem = idx & 255;
  int c = rem >> 6;
  int l = rem & 63;
  int ch = kt >> 1;
  int kbase = (kt & 1) * 32 + (l >> 4) * 8;
  int n = c * 16 + (l & 15);
  unsigned short* dst = &bpg[idx * 8];
#pragma unroll
  for (int j = 0; j < 8; ++j) {
    int k = kbase + j;
    float v;
    if (ch == 0)      v = w[k * 64 + n] - w[8192 + k * 64 + n];
    else if (ch == 1) v = w[4096 + k * 64 + n];
    else              v = 2.0f * w[8192 + k * 64 + n];
    dst[j] = f2bf(v);
  }
}

// ---------------- x (fp32) -> bf16 copy --------------------------------------
__global__ __launch_bounds__(256) void k_cvt(const float* __restrict__ x, unsigned short* __restrict__ xb) {
  int i = blockIdx.x * 256 + threadIdx.x;  // float4-quad index
  if (i >= BN_ROWS * 16) return;
  float4 v = ((const float4*)x)[i];
  ushort4 h;
  h.x = f2bf(v.x); h.y = f2bf(v.y); h.z = f2bf(v.z); h.w = f2bf(v.w);
  ((ushort4*)xb)[i] = h;
}

// ---------------- SPMM: dst[b,n,:] = sum_e lap_e * src[b,col_e,:] ------------
// One wave per NODE, BOTH batches. lane = (edge-slot g = l>>3) x (channel
// group cg = l&7). Per 8 edges: 1 per-lane 4B ccv load + 2 uint4 gathers.
// Output always bf16 (Z is consumed as bf16 by the MFMA gemm anyway).
#define UNPK_FMA(Q, A0, A1, A2, A3, A4, A5, A6, A7, V) \
  A0 += (V) * lof(Q.x); A1 += (V) * hif(Q.x); \
  A2 += (V) * lof(Q.y); A3 += (V) * hif(Q.y); \
  A4 += (V) * lof(Q.z); A5 += (V) * hif(Q.z); \
  A6 += (V) * lof(Q.w); A7 += (V) * hif(Q.w);

#define RED3(A) { A += __shfl_xor(A, 8); A += __shfl_xor(A, 16); A += __shfl_xor(A, 32); }

__global__ __launch_bounds__(256) void k_spmm(const unsigned short* __restrict__ src,
                                              unsigned short* __restrict__ dst,
                                              const int* __restrict__ rowptr, const int* __restrict__ deg,
                                              const unsigned int* __restrict__ ccv) {
  int n = (blockIdx.x * 256 + threadIdx.x) >> 6;
  int lane = threadIdx.x & 63;
  if (n >= N_NODES) return;
  const int g = lane >> 3;
  const int cg = lane & 7;
  const unsigned short* s0 = src;
  const unsigned short* s1 = src + (size_t)N_NODES * N_C;
  int r0 = rowptr[n];
  int end = r0 + deg[n];
  float a00 = 0, a01 = 0, a02 = 0, a03 = 0, a04 = 0, a05 = 0, a06 = 0, a07 = 0;
  float a10 = 0, a11 = 0, a12 = 0, a13 = 0, a14 = 0, a15 = 0, a16 = 0, a17 = 0;
#pragma unroll 2
  for (int i = r0; i < end; i += 8) {
    int idx = i + g;
    bool ok = idx < end;
    unsigned int pe = ccv[ok ? idx : (end - 1)];
    float val = ok ? hif(pe) : 0.0f;              // bf16 val sits in high half
    size_t off = (size_t)(pe & 0xFFFFu) * N_C + cg * 8;  // ushort units; 16B aligned
    uint4 q0 = *(const uint4*)(s0 + off);
    uint4 q1 = *(const uint4*)(s1 + off);
    UNPK_FMA(q0, a00, a01, a02, a03, a04, a05, a06, a07, val)
    UNPK_FMA(q1, a10, a11, a12, a13, a14, a15, a16, a17, val)
  }
  RED3(a00) RED3(a01) RED3(a02) RED3(a03) RED3(a04) RED3(a05) RED3(a06) RED3(a07)
  RED3(a10) RED3(a11) RED3(a12) RED3(a13) RED3(a14) RED3(a15) RED3(a16) RED3(a17)
  if (g == 0) {
    uint4 o;
    o.x = (unsigned)f2bf(a00) | ((unsigned)f2bf(a01) << 16);
    o.y = (unsigned)f2bf(a02) | ((unsigned)f2bf(a03) << 16);
    o.z = (unsigned)f2bf(a04) | ((unsigned)f2bf(a05) << 16);
    o.w = (unsigned)f2bf(a06) | ((unsigned)f2bf(a07) << 16);
    *(uint4*)(dst + (size_t)n * N_C + cg * 8) = o;
  } else if (g == 1) {
    uint4 o;
    o.x = (unsigned)f2bf(a10) | ((unsigned)f2bf(a11) << 16);
    o.y = (unsigned)f2bf(a12) | ((unsigned)f2bf(a13) << 16);
    o.z = (unsigned)f2bf(a14) | ((unsigned)f2bf(a15) << 16);
    o.w = (unsigned)f2bf(a16) | ((unsigned)f2bf(a17) << 16);
    *(uint4*)(dst + ((size_t)N_NODES + n) * N_C + cg * 8) = o;
  }
}

// ---------------- MFMA GEMM: out = [x|Tx1|Z] @ [W0-W2; W1; 2W2] + bias -------
// All three A-operands bf16 in ws (Z no longer round-trips fp32 through out;
// no in-place aliasing). 128 rows/block; wave owns 32 rows = 2 sub-tiles.
// Stage: 6 coalesced 16B loads/thread -> conflict-free ds_write_b128. Then 12
// independent 16B A-loads, per c-tile one B-frag read set feeding two
// independent 6-MFMA chains. C/D: col=lane&15, row=(lane>>4)*4+reg (m89).
__global__ __launch_bounds__(256) void k_gemm(const unsigned short* __restrict__ xb,
                                              const unsigned short* __restrict__ t1h,
                                              const unsigned short* __restrict__ zh,
                                              const unsigned short* __restrict__ bpg,
                                              const float* __restrict__ bias,
                                              float* __restrict__ out) {
  __shared__ unsigned short bp[12288];  // 24KB packed B fragments
  const int t = threadIdx.x;
#pragma unroll
  for (int i = 0; i < 6; ++i) {
    int idx = i * 256 + t;
    *(uint4*)&bp[idx * 8] = *(const uint4*)&bpg[idx * 8];
  }
  __syncthreads();

  const int wid = t >> 6;
  const int lane = t & 63;
  const size_t wbase = (size_t)blockIdx.x * 128 + (size_t)wid * 32;  // wave's 32 rows
  const int arow = lane & 15;
  const int ko = (lane >> 4) * 8;
  size_t rowA = wbase + arow;
  size_t rowB = wbase + 16 + arow;
  if (rowA > (size_t)(BN_ROWS - 1)) rowA = BN_ROWS - 1;  // clamped loads only
  if (rowB > (size_t)(BN_ROWS - 1)) rowB = BN_ROWS - 1;

  // ---- 12 independent 16B loads (6 per sub-tile) ----
  const unsigned short* xpA = xb + rowA * 64 + ko;
  const unsigned short* tpA = t1h + rowA * 64 + ko;
  const unsigned short* zpA = zh + rowA * 64 + ko;
  const unsigned short* xpB = xb + rowB * 64 + ko;
  const unsigned short* tpB = t1h + rowB * 64 + ko;
  const unsigned short* zpB = zh + rowB * 64 + ko;
  short8 axA0 = *(const short8*)(xpA);
  short8 axA1 = *(const short8*)(xpA + 32);
  short8 atA0 = *(const short8*)(tpA);
  short8 atA1 = *(const short8*)(tpA + 32);
  short8 azA0 = *(const short8*)(zpA);
  short8 azA1 = *(const short8*)(zpA + 32);
  short8 axB0 = *(const short8*)(xpB);
  short8 axB1 = *(const short8*)(xpB + 32);
  short8 atB0 = *(const short8*)(tpB);
  short8 atB1 = *(const short8*)(tpB + 32);
  short8 azB0 = *(const short8*)(zpB);
  short8 azB1 = *(const short8*)(zpB + 32);

  const int col = lane & 15;
  const int rgrp = lane >> 4;

#pragma unroll
  for (int c = 0; c < 4; ++c) {
    const unsigned short* bb = bp + c * 512;
    short8 b0 = *(const short8*)(bb + (0 * 256 + lane) * 8);
    short8 b1 = *(const short8*)(bb + (1 * 256 + lane) * 8);
    short8 b2 = *(const short8*)(bb + (2 * 256 + lane) * 8);
    short8 b3 = *(const short8*)(bb + (3 * 256 + lane) * 8);
    short8 b4 = *(const short8*)(bb + (4 * 256 + lane) * 8);
    short8 b5 = *(const short8*)(bb + (5 * 256 + lane) * 8);
    f32x4 accA = {0.f, 0.f, 0.f, 0.f};
    f32x4 accB = {0.f, 0.f, 0.f, 0.f};
    accA = __builtin_amdgcn_mfma_f32_16x16x32_bf16(axA0, b0, accA, 0, 0, 0);
    accB = __builtin_amdgcn_mfma_f32_16x16x32_bf16(axB0, b0, accB, 0, 0, 0);
    accA = __builtin_amdgcn_mfma_f32_16x16x32_bf16(axA1, b1, accA, 0, 0, 0);
    accB = __builtin_amdgcn_mfma_f32_16x16x32_bf16(axB1, b1, accB, 0, 0, 0);
    accA = __builtin_amdgcn_mfma_f32_16x16x32_bf16(atA0, b2, accA, 0, 0, 0);
    accB = __builtin_amdgcn_mfma_f32_16x16x32_bf16(atB0, b2, accB, 0, 0, 0);
    accA = __builtin_amdgcn_mfma_f32_16x16x32_bf16(atA1, b3, accA, 0, 0, 0);
    accB = __builtin_amdgcn_mfma_f32_16x16x32_bf16(atB1, b3, accB, 0, 0, 0);
    accA = __builtin_amdgcn_mfma_f32_16x16x32_bf16(azA0, b4, accA, 0, 0, 0);
    accB = __builtin_amdgcn_mfma_f32_16x16x32_bf16(azB0, b4, accB, 0, 0, 0);
    accA = __builtin_amdgcn_mfma_f32_16x16x32_bf16(azA1, b5, accA, 0, 0, 0);
    accB = __builtin_amdgcn_mfma_f32_16x16x32_bf16(azB1, b5, accB, 0, 0, 0);
    const float bcol = bias[c * 16 + col];
#pragma unroll
    for (int j = 0; j < 4; ++j) {
      size_t rA = wbase + (size_t)(rgrp * 4 + j);
      size_t rB = wbase + 16 + (size_t)(rgrp * 4 + j);
      if (rA < BN_ROWS) out[rA * 64 + c * 16 + col] = accA[j] + bcol;
      if (rB < BN_ROWS) out[rB * 64 + c * 16 + col] = accB[j] + bcol;
    }
  }
}

extern "C" void kernel_launch(void* const* d_in, const int* in_sizes, int n_in,
                              void* d_out, int out_size, void* d_ws, size_t ws_size,
                              hipStream_t stream) {
  const float* x = (const float*)d_in[0];
  const int* ei = (const int*)d_in[1];        // [2, E] int32
  const float* ew = (const float*)d_in[2];
  const float* w = (const float*)d_in[3];     // [3,64,64]
  const float* bias = (const float*)d_in[4];  // [64]
  float* out = (float*)d_out;

  // workspace layout (4-byte units)
  int* ws32 = (int*)d_ws;
  const size_t NA = 50048;  // padded N (16B-alignment preserved)
  int* deg = ws32;                          // [0..N) degrees, [N] = counter
  int* counter = deg + N_NODES;
  int* cursor = ws32 + NA;                  // free after k_fill -> reused for bpg
  float* dis = (float*)(cursor + NA);
  int* rowptr = (int*)(dis + NA);
  unsigned int* ccv = (unsigned int*)(rowptr + NA);                    // E uints (4B packed)
  unsigned short* xb = (unsigned short*)(ccv + N_EDGES);               // BN_ROWS*64 bf16
  unsigned short* t1h = xb + (size_t)BN_ROWS * N_C;                    // BN_ROWS*64 bf16
  unsigned short* zh = t1h + (size_t)BN_ROWS * N_C;                    // BN_ROWS*64 bf16
  unsigned short* bpg = (unsigned short*)cursor;                       // 24KB, aliases cursor
  const size_t NEED = ((size_t)(4 * NA + N_EDGES) + (size_t)BN_ROWS * N_C / 2 * 3) * 4;
  if (ws_size < NEED) return;  // clean fail instead of corruption

  hipMemsetAsync(deg, 0, (N_NODES + 1) * sizeof(int), stream);  // deg + counter
  k_cvt<<<(BN_ROWS * 16 + 255) / 256, 256, 0, stream>>>(x, xb);
  k_deg<<<(N_EDGES + 255) / 256, 256, 0, stream>>>(ei, deg);
  k_offsets<<<(N_NODES + 255) / 256, 256, 0, stream>>>(deg, counter, rowptr, cursor, dis);
  k_fill<<<(N_EDGES + 255) / 256, 256, 0, stream>>>(ei, ew, dis, cursor, ccv);
  k_pack<<<6, 256, 0, stream>>>(w, bpg);  // cursor dead after k_fill
  // Tx1 = L x   (bf16, both batches per wave)
  k_spmm<<<(N_NODES * 64 + 255) / 256, 256, 0, stream>>>(xb, t1h, rowptr, deg, ccv);
  // Z = L Tx1   (bf16, into ws)
  k_spmm<<<(N_NODES * 64 + 255) / 256, 256, 0, stream>>>(t1h, zh, rowptr, deg, ccv);
  // out = [x|Tx1|Z] @ [W0-W2; W1; 2W2] + bias  (MFMA)
  k_gemm<<<(BN_ROWS + 127) / 128, 256, 0, stream>>>(xb, t1h, zh, bpg, bias, out);
}